// Round 5
// baseline (137.658 us; speedup 1.0000x reference)
//
#include <hip/hip_runtime.h>
#include <hip/hip_cooperative_groups.h>
#include <climits>

namespace cg = cooperative_groups;

#define HH 1024
#define WW 1024
#define DD 128
#define NPIX (HH * WW)
#define NBLK 256          // main grid: 4 image rows per block

// ws 4B-unit layout:
//   wsf[64..576)    M (4x128 row-major)
//   wsf[576..704)   c (128)
//   wsi[1024..1280) rminP | [1280..1536) rmaxP | [1536..1792) cminP
//   wsi[1792..2048) cmaxP | [2048..2304) cntP        (one entry per block)
//   wsf[6200..6712) warm-read dummies
//   wsf[8192..8192+128*256) partials, layout [feature][block]
#define RMINP 1024
#define RMAXP 1280
#define CMINP 1536
#define CMAXP 1792
#define CNTP  2048
#define PART  8192

// ---- stats for the block's 4 rows (needs sred[4][8] shared) ---------------
__device__ __forceinline__ void d_stats(const float* __restrict__ x0, int blk,
                                        int tid, int* __restrict__ wsi,
                                        int (*sred)[8]) {
    const float4* x4 = (const float4*)(x0) + (size_t)blk * 1024;
    int any0, any1, any2, any3;
    int cmn = INT_MAX, cmx = -1, cnt = 0;
    int c4 = 4 * tid;
    {
        float4 v;
        bool z0, z1, z2, z3;
        #define STAT_K(K, ANY)                                                 \
            v = x4[K * 256 + tid];                                             \
            z0 = v.x != 0.f; z1 = v.y != 0.f; z2 = v.z != 0.f; z3 = v.w != 0.f;\
            ANY = (int)(z0 | z1 | z2 | z3);                                    \
            if (ANY) {                                                         \
                cmn = min(cmn, z0 ? c4 : (z1 ? c4+1 : (z2 ? c4+2 : c4+3)));    \
                cmx = max(cmx, z3 ? c4+3 : (z2 ? c4+2 : (z1 ? c4+1 : c4)));    \
            }                                                                  \
            cnt += (int)z0 + (int)z1 + (int)z2 + (int)z3;
        STAT_K(0, any0) STAT_K(1, any1) STAT_K(2, any2) STAT_K(3, any3)
        #undef STAT_K
    }
    for (int off = 32; off >= 1; off >>= 1) {
        cmn = min(cmn, __shfl_xor(cmn, off, 64));
        cmx = max(cmx, __shfl_xor(cmx, off, 64));
        cnt += __shfl_xor(cnt, off, 64);
        any0 |= __shfl_xor(any0, off, 64);
        any1 |= __shfl_xor(any1, off, 64);
        any2 |= __shfl_xor(any2, off, 64);
        any3 |= __shfl_xor(any3, off, 64);
    }
    int wave = tid >> 6;
    if ((tid & 63) == 0) {
        sred[wave][0] = cmn; sred[wave][1] = cmx; sred[wave][2] = cnt;
        sred[wave][3] = any0; sred[wave][4] = any1;
        sred[wave][5] = any2; sred[wave][6] = any3;
    }
    __syncthreads();
    if (tid == 0) {
        int a = sred[0][0], b = sred[0][1], c = sred[0][2];
        int f0 = sred[0][3], f1 = sred[0][4], f2 = sred[0][5], f3 = sred[0][6];
        for (int w = 1; w < 4; ++w) {
            a = min(a, sred[w][0]); b = max(b, sred[w][1]); c += sred[w][2];
            f0 |= sred[w][3]; f1 |= sred[w][4]; f2 |= sred[w][5]; f3 |= sred[w][6];
        }
        int r0 = blk * 4;
        wsi[RMINP + blk] = f0 ? r0 : (f1 ? r0+1 : (f2 ? r0+2 : (f3 ? r0+3 : INT_MAX)));
        wsi[RMAXP + blk] = f3 ? r0+3 : (f2 ? r0+2 : (f1 ? r0+1 : (f0 ? r0 : -1)));
        wsi[CMINP + blk] = a;
        wsi[CMAXP + blk] = b;
        wsi[CNTP  + blk] = c;
    }
    __syncthreads();   // sred safe to reuse afterwards
}

// ---- M = W1@W2, c = b1@W2 + b2 (tid<128); warm W3 into L3 (tid>=128) ------
__device__ __forceinline__ void d_prep(const float* __restrict__ W1,
                                       const float* __restrict__ b1,
                                       const float* __restrict__ W2,
                                       const float* __restrict__ b2,
                                       const float* __restrict__ W3,
                                       float* __restrict__ wsf, int tid) {
    if (tid < 128) {
        int j = tid;
        float p0 = 0.f, p1 = 0.f, p2 = 0.f, p3 = 0.f, cc = 0.f;
        #pragma unroll 8
        for (int d = 0; d < DD; ++d) {
            float w2 = W2[d * DD + j];
            p0 = fmaf(W1[0 * DD + d], w2, p0);
            p1 = fmaf(W1[1 * DD + d], w2, p1);
            p2 = fmaf(W1[2 * DD + d], w2, p2);
            p3 = fmaf(W1[3 * DD + d], w2, p3);
            cc = fmaf(b1[d],          w2, cc);
        }
        wsf[64 + 0 * DD + j] = p0;
        wsf[64 + 1 * DD + j] = p1;
        wsf[64 + 2 * DD + j] = p2;
        wsf[64 + 3 * DD + j] = p3;
        wsf[576 + j] = cc + b2[j];
    } else {
        const float4* w34 = (const float4*)W3;
        float s = 0.f;
        for (int k = tid - 128; k < DD * DD / 4; k += 128) {
            float4 t4 = w34[k]; s += t4.x + t4.y + t4.z + t4.w;
        }
        wsf[6200 + tid] = s;   // keep warm loads alive
    }
}

// ---- main accumulate over the block's 4 rows -> partials[f][blk] -----------
__device__ __forceinline__ void d_main(const float* __restrict__ x0,
                                       const float* __restrict__ x1,
                                       float* __restrict__ wsf,
                                       const int* __restrict__ wsi,
                                       int blk, int tid,
                                       float2* sv, unsigned short* lidx,
                                       int* lcnt, int (*sred)[8], float* red) {
    if (tid == 0) *lcnt = 0;
    // reduce the 256 per-block stats partials (one per thread)
    int rmn = wsi[RMINP + tid], rmx = wsi[RMAXP + tid];
    int cmn = wsi[CMINP + tid], cmx = wsi[CMAXP + tid];
    for (int off = 32; off >= 1; off >>= 1) {
        rmn = min(rmn, __shfl_xor(rmn, off, 64));
        rmx = max(rmx, __shfl_xor(rmx, off, 64));
        cmn = min(cmn, __shfl_xor(cmn, off, 64));
        cmx = max(cmx, __shfl_xor(cmx, off, 64));
    }
    int wave = tid >> 6;
    if ((tid & 63) == 0) {
        sred[wave][0] = rmn; sred[wave][1] = rmx;
        sred[wave][2] = cmn; sred[wave][3] = cmx;
    }
    __syncthreads();   // also makes lcnt=0 visible before atomics below
    rmn = min(min(sred[0][0], sred[1][0]), min(sred[2][0], sred[3][0]));
    rmx = max(max(sred[0][1], sred[1][1]), max(sred[2][1], sred[3][1]));
    cmn = min(min(sred[0][2], sred[1][2]), min(sred[2][2], sred[3][2]));
    cmx = max(max(sred[0][3], sred[1][3]), max(sred[2][3], sred[3][3]));

    // stage 4 rows interleaved (v0,v1) + record exact-zero pixels (rare)
    const float4* x04 = (const float4*)(x0) + (size_t)blk * 1024;
    const float4* x14 = (const float4*)(x1) + (size_t)blk * 1024;
    float4* sv4 = (float4*)sv;
    #pragma unroll
    for (int k = 0; k < 4; ++k) {
        int i = k * 256 + tid;
        float4 va = x04[i];
        float4 vb = x14[i];
        sv4[2 * i]     = make_float4(va.x, vb.x, va.y, vb.y);
        sv4[2 * i + 1] = make_float4(va.z, vb.z, va.w, vb.w);
        int p4 = 4 * i;
        if (va.x == 0.f) { int p = atomicAdd(lcnt, 1); lidx[p] = (unsigned short)(p4 + 0); }
        if (va.y == 0.f) { int p = atomicAdd(lcnt, 1); lidx[p] = (unsigned short)(p4 + 1); }
        if (va.z == 0.f) { int p = atomicAdd(lcnt, 1); lidx[p] = (unsigned short)(p4 + 2); }
        if (va.w == 0.f) { int p = atomicAdd(lcnt, 1); lidx[p] = (unsigned short)(p4 + 3); }
    }
    __syncthreads();

    int j = tid & 127;   // feature
    int g = tid >> 7;    // column half
    float rs = 1.0f / (float)(rmx - rmn);
    float cs = 1.0f / (float)(cmx - cmn);
    float M2 = wsf[64 + 2 * DD + j];
    float M3 = wsf[64 + 3 * DD + j];
    float a0 = wsf[64 + 0 * DD + j] * rs;
    float a1 = wsf[64 + 1 * DD + j] * cs;
    float cp = wsf[576 + j] - (float)rmn * a0 - (float)cmn * a1;
    float a1x2 = a1 + a1;
    float colb = (float)(g * 512);

    float acc0 = 0.f, acc1 = 0.f;
    for (int r = 0; r < 4; ++r) {
        float t = fmaf((float)(blk * 4 + r), a0, fmaf(colb, a1, cp));
        const float4* p = sv4 + r * 512 + g * 256;
        #pragma unroll 8
        for (int q = 0; q < 256; ++q) {
            float4 v = p[q];                     // 2 px, LDS broadcast
            float d0 = fmaf(v.x, M2, fmaf(v.y, M3, t));
            float d1 = fmaf(v.z, M2, fmaf(v.w, M3, t + a1));
            acc0 += fmaxf(d0, 0.f);
            acc1 += fmaxf(d1, 0.f);
            t += a1x2;
        }
    }
    float acc = acc0 + acc1;

    int nz = *lcnt;      // subtract masked-out (zero) pixels
    for (int ii = 0; ii < nz; ++ii) {
        int px = lidx[ii];
        if (((px & 1023) >> 9) == g) {
            float2 v = sv[px];
            float tp = fmaf((float)(blk * 4 + (px >> 10)), a0,
                            fmaf((float)(px & 1023), a1, cp));
            acc -= fmaxf(fmaf(v.x, M2, fmaf(v.y, M3, tp)), 0.f);
        }
    }

    red[tid] = acc;
    __syncthreads();
    if (tid < 128) wsf[PART + tid * NBLK + blk] = red[tid] + red[tid + 128];
}

// ---- tail: count + per-feature sum + mean + 128x128 matvec (one block) ----
__device__ __forceinline__ void d_tail(const float* __restrict__ wsf,
                                       const int* __restrict__ wsi,
                                       const float* __restrict__ W3,
                                       const float* __restrict__ b3,
                                       float* __restrict__ out, int tid,
                                       float* ts /* >=896 floats */,
                                       int (*sred)[8]) {
    int wave = tid >> 6, lane = tid & 63;
    int c = wsi[CNTP + tid];
    for (int off = 32; off >= 1; off >>= 1) c += __shfl_xor(c, off, 64);
    if (lane == 0) sred[wave][0] = c;

    // per-feature sum: f = tid>>1, half = tid&1 over 128 blocks each
    {
        const float4* p = (const float4*)(wsf + PART + (tid >> 1) * NBLK + (tid & 1) * 128);
        float sx = 0.f, sy = 0.f, sz = 0.f, sw = 0.f;
        #pragma unroll 8
        for (int q = 0; q < 32; ++q) {
            float4 v = p[q];
            sx += v.x; sy += v.y; sz += v.z; sw += v.w;
        }
        ts[tid] = (sx + sy) + (sz + sw);
    }
    __syncthreads();
    float cntf = (float)(sred[0][0] + sred[1][0] + sred[2][0] + sred[3][0]);
    if (tid < 128) ts[256 + tid] = (ts[2 * tid] + ts[2 * tid + 1]) / cntf;  // m
    __syncthreads();

    float o0 = 0.f, o1 = 0.f;
    #pragma unroll 8
    for (int d = wave * 32; d < wave * 32 + 32; ++d) {
        float md = ts[256 + d];
        o0 = fmaf(md, W3[d * DD + lane],      o0);
        o1 = fmaf(md, W3[d * DD + lane + 64], o1);
    }
    ts[384 + wave * 128 + lane]      = o0;
    ts[384 + wave * 128 + lane + 64] = o1;
    __syncthreads();
    if (tid < 128)
        out[tid] = b3[tid] + ts[384 + tid] + ts[384 + 128 + tid]
                 + ts[384 + 256 + tid] + ts[384 + 384 + tid];
}

// ================= cooperative single-kernel path ===========================
__global__ void kcoop(const float* __restrict__ x0, const float* __restrict__ x1,
                      const float* __restrict__ W1, const float* __restrict__ b1,
                      const float* __restrict__ W2, const float* __restrict__ b2,
                      const float* __restrict__ W3, const float* __restrict__ b3,
                      float* __restrict__ out, float* __restrict__ wsf,
                      int* __restrict__ wsi) {
    __shared__ float2 sv[4096];
    __shared__ unsigned short lidx[4096];
    __shared__ float red[256];
    __shared__ int   sred[4][8];
    __shared__ int   lcnt;

    cg::grid_group grid = cg::this_grid();
    int blk = blockIdx.x, tid = threadIdx.x;

    d_stats(x0, blk, tid, wsi, sred);
    if (blk == 0) d_prep(W1, b1, W2, b2, W3, wsf, tid);
    __threadfence();
    grid.sync();

    d_main(x0, x1, wsf, wsi, blk, tid, sv, lidx, &lcnt, sred, red);
    __threadfence();
    grid.sync();

    if (blk == 0) d_tail(wsf, wsi, W3, b3, out, tid, (float*)sv, sred);
}

// ================= fallback 3-kernel path ===================================
__global__ __launch_bounds__(256) void kA2(const float* __restrict__ x0,
                                           const float* __restrict__ W1,
                                           const float* __restrict__ b1,
                                           const float* __restrict__ W2,
                                           const float* __restrict__ b2,
                                           const float* __restrict__ W3,
                                           float* __restrict__ wsf,
                                           int* __restrict__ wsi) {
    __shared__ int sred[4][8];
    int blk = blockIdx.x, tid = threadIdx.x;
    if (blk < NBLK) d_stats(x0, blk, tid, wsi, sred);
    else            d_prep(W1, b1, W2, b2, W3, wsf, tid);
}

__global__ __launch_bounds__(256) void kB2(const float* __restrict__ x0,
                                           const float* __restrict__ x1,
                                           float* __restrict__ wsf,
                                           const int* __restrict__ wsi) {
    __shared__ float2 sv[4096];
    __shared__ unsigned short lidx[4096];
    __shared__ float red[256];
    __shared__ int   sred[4][8];
    __shared__ int   lcnt;
    d_main(x0, x1, wsf, wsi, blockIdx.x, threadIdx.x, sv, lidx, &lcnt, sred, red);
}

__global__ __launch_bounds__(256) void kC2(const float* __restrict__ wsf,
                                           const int* __restrict__ wsi,
                                           const float* __restrict__ W3,
                                           const float* __restrict__ b3,
                                           float* __restrict__ out) {
    __shared__ float ts[896];
    __shared__ int   sred[4][8];
    d_tail(wsf, wsi, W3, b3, out, threadIdx.x, ts, sred);
}

extern "C" void kernel_launch(void* const* d_in, const int* in_sizes, int n_in,
                              void* d_out, int out_size, void* d_ws, size_t ws_size,
                              hipStream_t stream) {
    const float* x  = (const float*)d_in[0];
    const float* x0 = x;
    const float* x1 = x + NPIX;
    const float* W1 = (const float*)d_in[1];
    const float* b1 = (const float*)d_in[2];
    const float* W2 = (const float*)d_in[3];
    const float* b2 = (const float*)d_in[4];
    const float* W3 = (const float*)d_in[5];
    const float* b3 = (const float*)d_in[6];
    float* outp = (float*)d_out;
    float* wsf  = (float*)d_ws;
    int*   wsi  = (int*)d_ws;

    void* args[] = {(void*)&x0, (void*)&x1, (void*)&W1, (void*)&b1, (void*)&W2,
                    (void*)&b2, (void*)&W3, (void*)&b3, (void*)&outp,
                    (void*)&wsf, (void*)&wsi};
    hipError_t err = hipLaunchCooperativeKernel((void*)kcoop, dim3(NBLK), dim3(256),
                                                args, 0, stream);
    if (err != hipSuccess) {
        // deterministic fallback: same device bodies, kernel-boundary sync
        hipLaunchKernelGGL(kA2, dim3(NBLK + 1), dim3(256), 0, stream,
                           x0, W1, b1, W2, b2, W3, wsf, wsi);
        hipLaunchKernelGGL(kB2, dim3(NBLK), dim3(256), 0, stream, x0, x1, wsf, wsi);
        hipLaunchKernelGGL(kC2, dim3(1), dim3(256), 0, stream, wsf, wsi, W3, b3, outp);
    }
}

// Round 6
// 44.688 us; speedup vs baseline: 3.0804x; 3.0804x over previous
//
#include <hip/hip_runtime.h>
#include <climits>

#define HH 1024
#define WW 1024
#define DD 128
#define NPIX (HH * WW)
#define NSB 256    // stats blocks (4 rows each)
#define NBB 512    // main blocks (2 rows each)

// ws 4B-unit layout:
//   wsf[64..576)    M (4x128 row-major)
//   wsf[576..704)   c (128)
//   wsi[1024..1280) rminP | [1280..1536) rmaxP | [1536..1792) cminP
//   wsi[1792..2048) cmaxP | [2048..2304) cntP     (one per stats block)
//   wsf[8192..8192+128*512) partials, layout [feature][block]
#define RMINP 1024
#define RMAXP 1280
#define CMINP 1536
#define CMAXP 1792
#define CNTP  2048
#define PART  8192

typedef _Float16 f16;
typedef __attribute__((ext_vector_type(8)))  _Float16 f16x8;
typedef __attribute__((ext_vector_type(16))) float    f32x16;

// ---- stats for a block's 4 rows (proven in rounds 4/5) ---------------------
__device__ __forceinline__ void d_stats(const float* __restrict__ x0, int blk,
                                        int tid, int* __restrict__ wsi,
                                        int (*sred)[8]) {
    const float4* x4 = (const float4*)(x0) + (size_t)blk * 1024;
    int any0, any1, any2, any3;
    int cmn = INT_MAX, cmx = -1, cnt = 0;
    int c4 = 4 * tid;
    {
        float4 v;
        bool z0, z1, z2, z3;
        #define STAT_K(K, ANY)                                                 \
            v = x4[K * 256 + tid];                                             \
            z0 = v.x != 0.f; z1 = v.y != 0.f; z2 = v.z != 0.f; z3 = v.w != 0.f;\
            ANY = (int)(z0 | z1 | z2 | z3);                                    \
            if (ANY) {                                                         \
                cmn = min(cmn, z0 ? c4 : (z1 ? c4+1 : (z2 ? c4+2 : c4+3)));    \
                cmx = max(cmx, z3 ? c4+3 : (z2 ? c4+2 : (z1 ? c4+1 : c4)));    \
            }                                                                  \
            cnt += (int)z0 + (int)z1 + (int)z2 + (int)z3;
        STAT_K(0, any0) STAT_K(1, any1) STAT_K(2, any2) STAT_K(3, any3)
        #undef STAT_K
    }
    for (int off = 32; off >= 1; off >>= 1) {
        cmn = min(cmn, __shfl_xor(cmn, off, 64));
        cmx = max(cmx, __shfl_xor(cmx, off, 64));
        cnt += __shfl_xor(cnt, off, 64);
        any0 |= __shfl_xor(any0, off, 64);
        any1 |= __shfl_xor(any1, off, 64);
        any2 |= __shfl_xor(any2, off, 64);
        any3 |= __shfl_xor(any3, off, 64);
    }
    int wave = tid >> 6;
    if ((tid & 63) == 0) {
        sred[wave][0] = cmn; sred[wave][1] = cmx; sred[wave][2] = cnt;
        sred[wave][3] = any0; sred[wave][4] = any1;
        sred[wave][5] = any2; sred[wave][6] = any3;
    }
    __syncthreads();
    if (tid == 0) {
        int a = sred[0][0], b = sred[0][1], c = sred[0][2];
        int f0 = sred[0][3], f1 = sred[0][4], f2 = sred[0][5], f3 = sred[0][6];
        for (int w = 1; w < 4; ++w) {
            a = min(a, sred[w][0]); b = max(b, sred[w][1]); c += sred[w][2];
            f0 |= sred[w][3]; f1 |= sred[w][4]; f2 |= sred[w][5]; f3 |= sred[w][6];
        }
        int r0 = blk * 4;
        wsi[RMINP + blk] = f0 ? r0 : (f1 ? r0+1 : (f2 ? r0+2 : (f3 ? r0+3 : INT_MAX)));
        wsi[RMAXP + blk] = f3 ? r0+3 : (f2 ? r0+2 : (f1 ? r0+1 : (f0 ? r0 : -1)));
        wsi[CMINP + blk] = a;
        wsi[CMAXP + blk] = b;
        wsi[CNTP  + blk] = c;
    }
}

// ---- kA: 256 stats blocks + 1 prep block (M = W1@W2, c = b1@W2 + b2) ------
__global__ __launch_bounds__(256) void kA(const float* __restrict__ x0,
                                          const float* __restrict__ W1,
                                          const float* __restrict__ b1,
                                          const float* __restrict__ W2,
                                          const float* __restrict__ b2,
                                          float* __restrict__ wsf,
                                          int* __restrict__ wsi) {
    __shared__ int sred[4][8];
    int blk = blockIdx.x, tid = threadIdx.x;
    if (blk < NSB) { d_stats(x0, blk, tid, wsi, sred); return; }
    if (tid < 128) {
        int j = tid;
        float p0 = 0.f, p1 = 0.f, p2 = 0.f, p3 = 0.f, cc = 0.f;
        #pragma unroll 8
        for (int d = 0; d < DD; ++d) {
            float w2 = W2[d * DD + j];
            p0 = fmaf(W1[0 * DD + d], w2, p0);
            p1 = fmaf(W1[1 * DD + d], w2, p1);
            p2 = fmaf(W1[2 * DD + d], w2, p2);
            p3 = fmaf(W1[3 * DD + d], w2, p3);
            cc = fmaf(b1[d],          w2, cc);
        }
        wsf[64 + 0 * DD + j] = p0;
        wsf[64 + 1 * DD + j] = p1;
        wsf[64 + 2 * DD + j] = p2;
        wsf[64 + 3 * DD + j] = p3;
        wsf[576 + j] = cc + b2[j];
    }
}

// ---- kB: MFMA main accumulate. 2 image rows per block, no LDS in hot loop --
// Wave w: row = 2*blk + (w>>1), col half = (w&1)*512. Lane<32 owns pixel
// col = colbase + t*32 + (lane&31). A k-slots (f16): (v0, v1, dcol, 0...);
// B k-slots: (M2[j], M3[j], a1h[j], 0...); C = cp + a0*row + a1*colbase (f32).
__global__ __launch_bounds__(256) void kB(const float* __restrict__ x0,
                                          const float* __restrict__ x1,
                                          float* __restrict__ wsf,
                                          const int* __restrict__ wsi) {
    __shared__ float lred[4][128];
    __shared__ int   sred[4][4];
    __shared__ int   zlist[2048];
    __shared__ int   zcnt;

    int tid = threadIdx.x, blk = blockIdx.x;
    int lane = tid & 63, wv = tid >> 6;
    bool lo = lane < 32;
    int j32 = lane & 31;

    if (tid == 0) zcnt = 0;

    // reduce the 256 stats partials
    int rmn = wsi[RMINP + tid], rmx = wsi[RMAXP + tid];
    int cmn = wsi[CMINP + tid], cmx = wsi[CMAXP + tid];
    for (int off = 32; off >= 1; off >>= 1) {
        rmn = min(rmn, __shfl_xor(rmn, off, 64));
        rmx = max(rmx, __shfl_xor(rmx, off, 64));
        cmn = min(cmn, __shfl_xor(cmn, off, 64));
        cmx = max(cmx, __shfl_xor(cmx, off, 64));
    }
    if ((tid & 63) == 0) {
        sred[wv][0] = rmn; sred[wv][1] = rmx;
        sred[wv][2] = cmn; sred[wv][3] = cmx;
    }
    __syncthreads();   // sred + zcnt visible
    rmn = min(min(sred[0][0], sred[1][0]), min(sred[2][0], sred[3][0]));
    rmx = max(max(sred[0][1], sred[1][1]), max(sred[2][1], sred[3][1]));
    cmn = min(min(sred[0][2], sred[1][2]), min(sred[2][2], sred[3][2]));
    cmx = max(max(sred[0][3], sred[1][3]), max(sred[2][3], sred[3][3]));

    float rs = 1.0f / (float)(rmx - rmn);
    float cs = 1.0f / (float)(cmx - cmn);
    int row = blk * 2 + (wv >> 1);
    int colbase = (wv & 1) * 512;

    // per-j-tile fragments
    f16x8 B0, B1, B2, B3;
    f32x16 C0, C1, C2, C3;
    float a1r0, a1r1, a1r2, a1r3;
    #define MKJT(JT, BV, CV, A1R) {                                            \
        int idx = JT * 32 + j32;                                               \
        float M2f = wsf[64 + 2 * DD + idx];                                    \
        float M3f = wsf[64 + 3 * DD + idx];                                    \
        float a0f = wsf[64 + 0 * DD + idx] * rs;                               \
        float a1f = wsf[64 + 1 * DD + idx] * cs;                               \
        float cpf = wsf[576 + idx] - (float)rmn * a0f - (float)cmn * a1f;      \
        float cval = fmaf(a0f, (float)row, fmaf(a1f, (float)colbase, cpf));    \
        f16 a1h = (f16)a1f;  A1R = (float)a1h;                                 \
        _Float16 z = (_Float16)0.f;                                            \
        BV[0] = z; BV[1] = z; BV[2] = z; BV[3] = z;                            \
        BV[4] = z; BV[5] = z; BV[6] = z; BV[7] = z;                            \
        if (lo) { BV[0] = (f16)M2f; BV[1] = (f16)M3f; BV[2] = a1h; }           \
        _Pragma("unroll")                                                      \
        for (int i = 0; i < 16; ++i) CV[i] = cval; }
    MKJT(0, B0, C0, a1r0)
    MKJT(1, B1, C1, a1r1)
    MKJT(2, B2, C2, a1r2)
    MKJT(3, B3, C3, a1r3)
    #undef MKJT

    const float* p0 = x0 + (size_t)row * WW + colbase + j32;
    const float* p1 = x1 + (size_t)row * WW + colbase + j32;
    float acc0 = 0.f, acc1 = 0.f, acc2 = 0.f, acc3 = 0.f;
    float j32f = (float)j32;

    f16x8 A;
    {
        _Float16 z = (_Float16)0.f;
        #pragma unroll
        for (int i = 0; i < 8; ++i) A[i] = z;
    }

    #pragma unroll 2
    for (int t = 0; t < 16; ++t) {
        float v0f = 0.f, v1f = 0.f;
        if (lo) { v0f = p0[t * 32]; v1f = p1[t * 32]; }
        if (lo && v0f == 0.f) {   // masked-out pixel (rare): remember it
            int q = atomicAdd(&zcnt, 1);
            zlist[q] = ((wv >> 1) << 12) | (colbase + t * 32 + j32);
        }
        if (lo) {
            A[0] = (f16)v0f;
            A[1] = (f16)v1f;
            A[2] = (f16)(j32f + (float)(t * 32));   // dcol, f16-exact (<512)
        }
        f32x16 D;
        D = __builtin_amdgcn_mfma_f32_32x32x16_f16(A, B0, C0, 0, 0, 0);
        #pragma unroll
        for (int i = 0; i < 16; ++i) acc0 += fmaxf(D[i], 0.f);
        D = __builtin_amdgcn_mfma_f32_32x32x16_f16(A, B1, C1, 0, 0, 0);
        #pragma unroll
        for (int i = 0; i < 16; ++i) acc1 += fmaxf(D[i], 0.f);
        D = __builtin_amdgcn_mfma_f32_32x32x16_f16(A, B2, C2, 0, 0, 0);
        #pragma unroll
        for (int i = 0; i < 16; ++i) acc2 += fmaxf(D[i], 0.f);
        D = __builtin_amdgcn_mfma_f32_32x32x16_f16(A, B3, C3, 0, 0, 0);
        #pragma unroll
        for (int i = 0; i < 16; ++i) acc3 += fmaxf(D[i], 0.f);
    }

    // subtract masked-out pixels' relu(a1h*dcol + cval) contributions
    __syncthreads();   // zlist complete
    int nz = zcnt;
    int hsel = lane >> 5;
    for (int ii = 0; ii < nz; ++ii) {
        int pc = zlist[ii];
        int zrbit = pc >> 12;
        int zc = pc & 4095;
        if (zrbit == (wv >> 1) && (zc >> 9) == (wv & 1) &&
            (((zc >> 2) & 1) == hsel)) {
            float dcolf = (float)(zc - colbase);
            float t0 = fmaf(a1r0, dcolf, C0[0]); acc0 -= fmaxf(t0, 0.f);
            float t1 = fmaf(a1r1, dcolf, C1[0]); acc1 -= fmaxf(t1, 0.f);
            float t2 = fmaf(a1r2, dcolf, C2[0]); acc2 -= fmaxf(t2, 0.f);
            float t3 = fmaf(a1r3, dcolf, C3[0]); acc3 -= fmaxf(t3, 0.f);
        }
    }

    // combine lane halves (same j, disjoint pixel rows), then waves
    acc0 += __shfl_xor(acc0, 32, 64);
    acc1 += __shfl_xor(acc1, 32, 64);
    acc2 += __shfl_xor(acc2, 32, 64);
    acc3 += __shfl_xor(acc3, 32, 64);
    if (lo) {
        lred[wv][0 * 32 + j32] = acc0;
        lred[wv][1 * 32 + j32] = acc1;
        lred[wv][2 * 32 + j32] = acc2;
        lred[wv][3 * 32 + j32] = acc3;
    }
    __syncthreads();
    if (tid < 128) {
        float s = lred[0][tid] + lred[1][tid] + lred[2][tid] + lred[3][tid];
        wsf[PART + tid * NBB + blk] = s;
    }
}

// ---- kC: count + per-feature sum + mean + 128x128 matvec (one block) ------
__global__ __launch_bounds__(256) void kC(const float* __restrict__ wsf,
                                          const int* __restrict__ wsi,
                                          const float* __restrict__ W3,
                                          const float* __restrict__ b3,
                                          float* __restrict__ out) {
    __shared__ float sm[128];
    __shared__ float s2[256];
    __shared__ int   csum[4];
    int tid = threadIdx.x, wv = tid >> 6, lane = tid & 63;

    int c = wsi[CNTP + tid];
    for (int off = 32; off >= 1; off >>= 1) c += __shfl_xor(c, off, 64);
    if (lane == 0) csum[wv] = c;

    {   // feature f = tid>>1, half = tid&1 over 512 block-partials
        const float4* p = (const float4*)(wsf + PART + (tid >> 1) * NBB + (tid & 1) * 256);
        float sx = 0.f, sy = 0.f, sz = 0.f, sw = 0.f;
        #pragma unroll 8
        for (int q = 0; q < 64; ++q) {
            float4 v = p[q];
            sx += v.x; sy += v.y; sz += v.z; sw += v.w;
        }
        s2[tid] = (sx + sy) + (sz + sw);
    }
    __syncthreads();
    float cntf = (float)(csum[0] + csum[1] + csum[2] + csum[3]);
    if (tid < 128) sm[tid] = (s2[2 * tid] + s2[2 * tid + 1]) / cntf;
    __syncthreads();

    int col = tid & 127, h = tid >> 7;
    float o = 0.f;
    #pragma unroll 8
    for (int d = h * 64; d < h * 64 + 64; ++d)
        o = fmaf(sm[d], W3[d * DD + col], o);
    s2[tid] = o;
    __syncthreads();
    if (tid < 128) out[tid] = b3[tid] + s2[tid] + s2[tid + 128];
}

extern "C" void kernel_launch(void* const* d_in, const int* in_sizes, int n_in,
                              void* d_out, int out_size, void* d_ws, size_t ws_size,
                              hipStream_t stream) {
    const float* x  = (const float*)d_in[0];
    const float* x0 = x;
    const float* x1 = x + NPIX;
    const float* W1 = (const float*)d_in[1];
    const float* b1 = (const float*)d_in[2];
    const float* W2 = (const float*)d_in[3];
    const float* b2 = (const float*)d_in[4];
    const float* W3 = (const float*)d_in[5];
    const float* b3 = (const float*)d_in[6];
    float* outp = (float*)d_out;
    float* wsf  = (float*)d_ws;
    int*   wsi  = (int*)d_ws;

    hipLaunchKernelGGL(kA, dim3(NSB + 1), dim3(256), 0, stream,
                       x0, W1, b1, W2, b2, wsf, wsi);
    hipLaunchKernelGGL(kB, dim3(NBB), dim3(256), 0, stream, x0, x1, wsf, wsi);
    hipLaunchKernelGGL(kC, dim3(1), dim3(256), 0, stream, wsf, wsi, W3, b3, outp);
}

// Round 7
// 33.426 us; speedup vs baseline: 4.1183x; 1.3369x over previous
//
#include <hip/hip_runtime.h>
#include <climits>

#define HH 1024
#define WW 1024
#define DD 128
#define NPIX (HH * WW)
#define NSB 256    // stats blocks (4 rows each) in kA
#define NBB 512    // main blocks (2 rows each) in kB

// ws 4B-unit layout:
//   wsf[64..576)    M (4x128 row-major)
//   wsf[576..704)   c (128)
//   wsi[1024..1280) rminP | [1280..1536) rmaxP | [1536..1792) cminP
//   wsi[1792..2048) cmaxP | [2048..2304) cntP     (one per stats block)
//   wsf[8192..8192+128*512) partials, layout [feature][block] (per-feature contiguous)
#define RMINP 1024
#define RMAXP 1280
#define CMINP 1536
#define CMAXP 1792
#define CNTP  2048
#define PART  8192

// ---- stats for a block's 4 rows (proven rounds 4-6) ------------------------
__device__ __forceinline__ void d_stats(const float* __restrict__ x0, int blk,
                                        int tid, int* __restrict__ wsi,
                                        int (*sred)[8]) {
    const float4* x4 = (const float4*)(x0) + (size_t)blk * 1024;
    int any0, any1, any2, any3;
    int cmn = INT_MAX, cmx = -1, cnt = 0;
    int c4 = 4 * tid;
    {
        float4 v;
        bool z0, z1, z2, z3;
        #define STAT_K(K, ANY)                                                 \
            v = x4[K * 256 + tid];                                             \
            z0 = v.x != 0.f; z1 = v.y != 0.f; z2 = v.z != 0.f; z3 = v.w != 0.f;\
            ANY = (int)(z0 | z1 | z2 | z3);                                    \
            if (ANY) {                                                         \
                cmn = min(cmn, z0 ? c4 : (z1 ? c4+1 : (z2 ? c4+2 : c4+3)));    \
                cmx = max(cmx, z3 ? c4+3 : (z2 ? c4+2 : (z1 ? c4+1 : c4)));    \
            }                                                                  \
            cnt += (int)z0 + (int)z1 + (int)z2 + (int)z3;
        STAT_K(0, any0) STAT_K(1, any1) STAT_K(2, any2) STAT_K(3, any3)
        #undef STAT_K
    }
    for (int off = 32; off >= 1; off >>= 1) {
        cmn = min(cmn, __shfl_xor(cmn, off, 64));
        cmx = max(cmx, __shfl_xor(cmx, off, 64));
        cnt += __shfl_xor(cnt, off, 64);
        any0 |= __shfl_xor(any0, off, 64);
        any1 |= __shfl_xor(any1, off, 64);
        any2 |= __shfl_xor(any2, off, 64);
        any3 |= __shfl_xor(any3, off, 64);
    }
    int wave = tid >> 6;
    if ((tid & 63) == 0) {
        sred[wave][0] = cmn; sred[wave][1] = cmx; sred[wave][2] = cnt;
        sred[wave][3] = any0; sred[wave][4] = any1;
        sred[wave][5] = any2; sred[wave][6] = any3;
    }
    __syncthreads();
    if (tid == 0) {
        int a = sred[0][0], b = sred[0][1], c = sred[0][2];
        int f0 = sred[0][3], f1 = sred[0][4], f2 = sred[0][5], f3 = sred[0][6];
        for (int w = 1; w < 4; ++w) {
            a = min(a, sred[w][0]); b = max(b, sred[w][1]); c += sred[w][2];
            f0 |= sred[w][3]; f1 |= sred[w][4]; f2 |= sred[w][5]; f3 |= sred[w][6];
        }
        int r0 = blk * 4;
        wsi[RMINP + blk] = f0 ? r0 : (f1 ? r0+1 : (f2 ? r0+2 : (f3 ? r0+3 : INT_MAX)));
        wsi[RMAXP + blk] = f3 ? r0+3 : (f2 ? r0+2 : (f1 ? r0+1 : (f0 ? r0 : -1)));
        wsi[CMINP + blk] = a;
        wsi[CMAXP + blk] = b;
        wsi[CNTP  + blk] = c;
    }
}

// ---- kA: 256 stats blocks + 1 prep block (M, c, out = b3) ------------------
__global__ __launch_bounds__(256) void kA(const float* __restrict__ x0,
                                          const float* __restrict__ W1,
                                          const float* __restrict__ b1,
                                          const float* __restrict__ W2,
                                          const float* __restrict__ b2,
                                          const float* __restrict__ b3,
                                          float* __restrict__ out,
                                          float* __restrict__ wsf,
                                          int* __restrict__ wsi) {
    __shared__ int sred[4][8];
    int blk = blockIdx.x, tid = threadIdx.x;
    if (blk < NSB) { d_stats(x0, blk, tid, wsi, sred); return; }
    if (tid < 128) {
        int j = tid;
        float p0 = 0.f, p1 = 0.f, p2 = 0.f, p3 = 0.f, cc = 0.f;
        #pragma unroll 8
        for (int d = 0; d < DD; ++d) {
            float w2 = W2[d * DD + j];
            p0 = fmaf(W1[0 * DD + d], w2, p0);
            p1 = fmaf(W1[1 * DD + d], w2, p1);
            p2 = fmaf(W1[2 * DD + d], w2, p2);
            p3 = fmaf(W1[3 * DD + d], w2, p3);
            cc = fmaf(b1[d],          w2, cc);
        }
        wsf[64 + 0 * DD + j] = p0;
        wsf[64 + 1 * DD + j] = p1;
        wsf[64 + 2 * DD + j] = p2;
        wsf[64 + 3 * DD + j] = p3;
        wsf[576 + j] = cc + b2[j];
        out[j] = b3[j];              // seed output; kC accumulates atomically
    }
}

// ---- kB: LDS-broadcast main loop (round-3-proven core), 2 rows per block ---
// Thread (j = tid&127, g = tid>>7): feature j over row (2*blk + g), all 1024
// cols. Maskless relu-sum; exact-zero pixels recorded and subtracted after.
__global__ __launch_bounds__(256) void kB(const float* __restrict__ x0,
                                          const float* __restrict__ x1,
                                          float* __restrict__ wsf,
                                          const int* __restrict__ wsi) {
    __shared__ float2 sv[2048];            // (v0,v1) for 2 rows
    __shared__ float red[256];
    __shared__ int   sred[4][4];
    __shared__ unsigned short lidx[2048];
    __shared__ int   lcnt;

    int tid = threadIdx.x, blk = blockIdx.x;
    int wv = tid >> 6;

    if (tid == 0) lcnt = 0;

    // reduce the 256 stats partials (one per thread)
    int rmn = wsi[RMINP + tid], rmx = wsi[RMAXP + tid];
    int cmn = wsi[CMINP + tid], cmx = wsi[CMAXP + tid];
    for (int off = 32; off >= 1; off >>= 1) {
        rmn = min(rmn, __shfl_xor(rmn, off, 64));
        rmx = max(rmx, __shfl_xor(rmx, off, 64));
        cmn = min(cmn, __shfl_xor(cmn, off, 64));
        cmx = max(cmx, __shfl_xor(cmx, off, 64));
    }
    if ((tid & 63) == 0) {
        sred[wv][0] = rmn; sred[wv][1] = rmx;
        sred[wv][2] = cmn; sred[wv][3] = cmx;
    }
    __syncthreads();   // sred + lcnt visible
    rmn = min(min(sred[0][0], sred[1][0]), min(sred[2][0], sred[3][0]));
    rmx = max(max(sred[0][1], sred[1][1]), max(sred[2][1], sred[3][1]));
    cmn = min(min(sred[0][2], sred[1][2]), min(sred[2][2], sred[3][2]));
    cmx = max(max(sred[0][3], sred[1][3]), max(sred[2][3], sred[3][3]));

    // stage 2 rows interleaved (v0,v1); record exact-zero pixels (rare)
    const float4* x04 = (const float4*)(x0) + (size_t)blk * 512;
    const float4* x14 = (const float4*)(x1) + (size_t)blk * 512;
    float4* sv4 = (float4*)sv;
    #pragma unroll
    for (int k = 0; k < 2; ++k) {
        int i = k * 256 + tid;
        float4 va = x04[i];
        float4 vb = x14[i];
        sv4[2 * i]     = make_float4(va.x, vb.x, va.y, vb.y);
        sv4[2 * i + 1] = make_float4(va.z, vb.z, va.w, vb.w);
        int p4 = 4 * i;
        if (va.x == 0.f) { int p = atomicAdd(&lcnt, 1); lidx[p] = (unsigned short)(p4 + 0); }
        if (va.y == 0.f) { int p = atomicAdd(&lcnt, 1); lidx[p] = (unsigned short)(p4 + 1); }
        if (va.z == 0.f) { int p = atomicAdd(&lcnt, 1); lidx[p] = (unsigned short)(p4 + 2); }
        if (va.w == 0.f) { int p = atomicAdd(&lcnt, 1); lidx[p] = (unsigned short)(p4 + 3); }
    }
    __syncthreads();

    int j = tid & 127;   // feature
    int g = tid >> 7;    // row within block
    int row = blk * 2 + g;
    float rs = 1.0f / (float)(rmx - rmn);
    float cs = 1.0f / (float)(cmx - cmn);
    float M2 = wsf[64 + 2 * DD + j];
    float M3 = wsf[64 + 3 * DD + j];
    float a0 = wsf[64 + 0 * DD + j] * rs;
    float a1 = wsf[64 + 1 * DD + j] * cs;
    float cp = wsf[576 + j] - (float)rmn * a0 - (float)cmn * a1;
    float a1x2 = a1 + a1;

    float rowbase = fmaf((float)row, a0, cp);
    float t = rowbase;                     // col 0
    float acc0 = 0.f, acc1 = 0.f;
    const float4* p = sv4 + g * 512;       // this row's 512 float4s (2 px each)
    #pragma unroll 8
    for (int q = 0; q < 512; ++q) {
        float4 v = p[q];                   // wave-uniform -> LDS broadcast
        float d0 = fmaf(v.x, M2, fmaf(v.y, M3, t));
        float d1 = fmaf(v.z, M2, fmaf(v.w, M3, t + a1));
        acc0 += fmaxf(d0, 0.f);
        acc1 += fmaxf(d1, 0.f);
        t += a1x2;
    }
    float acc = acc0 + acc1;

    int nz = lcnt;     // subtract masked-out (zero) pixels
    for (int ii = 0; ii < nz; ++ii) {
        int px = lidx[ii];
        if ((px >> 10) == g) {
            float2 v = sv[px];
            float tp = fmaf((float)(px & 1023), a1, rowbase);
            acc -= fmaxf(fmaf(v.x, M2, fmaf(v.y, M3, tp)), 0.f);
        }
    }

    red[tid] = acc;
    __syncthreads();
    if (tid < 128) {
        // partial for this block = both rows, per-feature-contiguous layout
        wsf[PART + tid * NBB + blk] = red[tid] + red[tid + 128];
    }
}

// ---- kC: 128 blocks, one feature each: sum partials, mean, matvec-atomics --
__global__ __launch_bounds__(256) void kC(const float* __restrict__ wsf,
                                          const int* __restrict__ wsi,
                                          const float* __restrict__ W3,
                                          const float* __restrict__ b3,
                                          float* __restrict__ out) {
    __shared__ float sred[4];
    __shared__ int   cred[4];
    __shared__ float mf_sh;
    int f = blockIdx.x, tid = threadIdx.x;
    int wv = tid >> 6, lane = tid & 63;

    // total mask count (256 per-stats-block counts)
    int c = wsi[CNTP + tid];
    for (int off = 32; off >= 1; off >>= 1) c += __shfl_xor(c, off, 64);
    if (lane == 0) cred[wv] = c;

    // per-feature sum over 512 block-partials (contiguous -> coalesced)
    const float* p = wsf + PART + (size_t)f * NBB;
    float S = p[tid] + p[tid + 256];
    for (int off = 32; off >= 1; off >>= 1) S += __shfl_xor(S, off, 64);
    if (lane == 0) sred[wv] = S;
    __syncthreads();
    if (tid == 0) {
        float tot = (sred[0] + sred[1]) + (sred[2] + sred[3]);
        float cnt = (float)(cred[0] + cred[1] + cred[2] + cred[3]);
        mf_sh = tot / cnt;
    }
    __syncthreads();

    // out[j] += m_f * W3[f][j]  (row of W3 is contiguous; b3 seeded in kA)
    if (tid < 128) {
        float mf = mf_sh;
        atomicAdd(&out[tid], mf * W3[f * DD + tid]);
    }
}

extern "C" void kernel_launch(void* const* d_in, const int* in_sizes, int n_in,
                              void* d_out, int out_size, void* d_ws, size_t ws_size,
                              hipStream_t stream) {
    const float* x  = (const float*)d_in[0];
    const float* x0 = x;
    const float* x1 = x + NPIX;
    const float* W1 = (const float*)d_in[1];
    const float* b1 = (const float*)d_in[2];
    const float* W2 = (const float*)d_in[3];
    const float* b2 = (const float*)d_in[4];
    const float* W3 = (const float*)d_in[5];
    const float* b3 = (const float*)d_in[6];
    float* outp = (float*)d_out;
    float* wsf  = (float*)d_ws;
    int*   wsi  = (int*)d_ws;

    hipLaunchKernelGGL(kA, dim3(NSB + 1), dim3(256), 0, stream,
                       x0, W1, b1, W2, b2, b3, outp, wsf, wsi);
    hipLaunchKernelGGL(kB, dim3(NBB), dim3(256), 0, stream, x0, x1, wsf, wsi);
    hipLaunchKernelGGL(kC, dim3(DD), dim3(256), 0, stream, wsf, wsi, W3, b3, outp);
}